// Round 3
// baseline (478.107 us; speedup 1.0000x reference)
//
#include <hip/hip_runtime.h>
#include <hip/hip_bf16.h>

#define Bb   2
#define Ss   2048
#define Dd   2048
#define Hh   16
#define KVHh 4
#define HDd  128

typedef __bf16 bf16x8 __attribute__((ext_vector_type(8)));
typedef float f32x4 __attribute__((ext_vector_type(4)));

__device__ __forceinline__ unsigned short f2bf(float f) {
    unsigned u = __float_as_uint(f);
    unsigned r = (u + 0x7FFFu + ((u >> 16) & 1u)) >> 16;   // RNE
    return (unsigned short)r;
}
__device__ __forceinline__ float bfu2f(unsigned short u) {
    return __uint_as_float(((unsigned)u) << 16);
}

// async global->LDS, 16B per lane; lds base must be wave-uniform
#define GLOAD16(g, l) __builtin_amdgcn_global_load_lds( \
    (const __attribute__((address_space(1))) unsigned int*)(g), \
    (__attribute__((address_space(3))) unsigned int*)(l), 16, 0, 0)

// fp32 -> bf16 elementwise, 4 elems/thread
__global__ __launch_bounds__(256)
void cast_bf16(const float* __restrict__ X, unsigned short* __restrict__ Y)
{
    int idx = blockIdx.x * 256 + threadIdx.x;
    float4 v = reinterpret_cast<const float4*>(X)[idx];
    ushort4 o;
    o.x = f2bf(v.x); o.y = f2bf(v.y); o.z = f2bf(v.z); o.w = f2bf(v.w);
    reinterpret_cast<ushort4*>(Y)[idx] = o;
}

// W[K,N] fp32 -> WT[N,K] bf16
__global__ __launch_bounds__(256)
void wt_cast(const float* __restrict__ W, unsigned short* __restrict__ WT,
             int K, int N)
{
    __shared__ float tile[32][33];
    int k0 = blockIdx.x * 32, n0 = blockIdx.y * 32;
    int tx = threadIdx.x & 31, ty = threadIdx.x >> 5;   // 32 x 8
    #pragma unroll
    for (int i = 0; i < 32; i += 8)
        tile[ty + i][tx] = W[(size_t)(k0 + ty + i) * N + n0 + tx];
    __syncthreads();
    #pragma unroll
    for (int i = 0; i < 32; i += 8)
        WT[(size_t)(n0 + ty + i) * K + k0 + tx] = f2bf(tile[tx][ty + i]);
}

// C[M,N] = A[M,K] @ BT[N,K]^T, bf16 in, fp32 accumulate, fp32 or bf16 out.
// 128x128 tile, BK=32, 4 waves (2x2 of 64x64), global_load_lds staging.
template<bool BF16OUT>
__global__ __launch_bounds__(256)
void gemm_bt(const unsigned short* __restrict__ A,
             const unsigned short* __restrict__ BT,
             void* __restrict__ Cv, int M, int N, int K)
{
    __shared__ __align__(16) unsigned short sA[128 * 32];
    __shared__ __align__(16) unsigned short sB[128 * 32];
    const int tid  = threadIdx.x;
    const int wave = tid >> 6;
    const int lane = tid & 63;
    const int m    = lane & 15;
    const int quad = lane >> 4;
    const int wm   = wave >> 1, wn = wave & 1;
    const int m0   = blockIdx.y * 128, n0 = blockIdx.x * 128;

    const int srow = tid >> 2;          // 0..63
    const int skg  = (tid & 3) * 8;     // k-group *8 elems

    f32x4 acc[4][4];
    #pragma unroll
    for (int r = 0; r < 4; ++r)
        #pragma unroll
        for (int c = 0; c < 4; ++c) acc[r][c] = (f32x4){0.f, 0.f, 0.f, 0.f};

    const unsigned short* pa = A  + (size_t)(m0 + srow) * K + skg;
    const unsigned short* pb = BT + (size_t)(n0 + srow) * K + skg;
    unsigned short* la = &sA[wave * 16 * 32];   // wave-uniform LDS base
    unsigned short* lb = &sB[wave * 16 * 32];

    for (int k0 = 0; k0 < K; k0 += 32) {
        GLOAD16(pa + k0, la);
        GLOAD16(pa + (size_t)64 * K + k0, la + 64 * 32);
        GLOAD16(pb + k0, lb);
        GLOAD16(pb + (size_t)64 * K + k0, lb + 64 * 32);
        __syncthreads();
        bf16x8 af[4], bfr[4];
        #pragma unroll
        for (int r = 0; r < 4; ++r)
            af[r] = *reinterpret_cast<const bf16x8*>(
                &sA[(wm * 64 + r * 16 + m) * 32 + quad * 8]);
        #pragma unroll
        for (int c = 0; c < 4; ++c)
            bfr[c] = *reinterpret_cast<const bf16x8*>(
                &sB[(wn * 64 + c * 16 + m) * 32 + quad * 8]);
        #pragma unroll
        for (int r = 0; r < 4; ++r)
            #pragma unroll
            for (int c = 0; c < 4; ++c)
                acc[r][c] = __builtin_amdgcn_mfma_f32_16x16x32_bf16(
                    af[r], bfr[c], acc[r][c], 0, 0, 0);
        __syncthreads();
    }
    // C/D layout: row = quad*4 + e, col = m
    #pragma unroll
    for (int r = 0; r < 4; ++r)
        #pragma unroll
        for (int c = 0; c < 4; ++c)
            #pragma unroll
            for (int e = 0; e < 4; ++e) {
                size_t row = m0 + wm * 64 + r * 16 + quad * 4 + e;
                size_t col = n0 + wn * 64 + c * 16 + m;
                if (BF16OUT)
                    ((unsigned short*)Cv)[row * N + col] = f2bf(acc[r][c][e]);
                else
                    ((float*)Cv)[row * N + col] = acc[r][c][e];
            }
}

// In-place RoPE on bf16 X, rows of `rowstride`, head slice h*128.
__global__ __launch_bounds__(256)
void rope_bf(unsigned short* __restrict__ X, const float* __restrict__ cosT,
             const float* __restrict__ sinT, int nhshift, int rowstride,
             float scale, int total)
{
    int idx = blockIdx.x * 256 + threadIdx.x;
    if (idx >= total) return;
    int i   = idx & 63;
    int rh  = idx >> 6;                  // (b*S+s)*nh + h
    int row = rh >> nhshift;             // b*S + s
    int h   = rh & ((1 << nhshift) - 1);
    int s   = row & (Ss - 1);
    unsigned short* xp = X + (size_t)row * rowstride + h * HDd;
    float x1 = bfu2f(xp[i]);
    float x2 = bfu2f(xp[i + 64]);
    float c1 = cosT[s * HDd + i];
    float c2 = cosT[s * HDd + i + 64];
    float s1 = sinT[s * HDd + i];
    float s2 = sinT[s * HDd + i + 64];
    xp[i]      = f2bf((x1 * c1 - x2 * s1) * scale);
    xp[i + 64] = f2bf((x2 * c2 + x1 * s2) * scale);
}

// V (cols 512.. of KVraw [B*S,1024] bf16) -> VT [B,KVH,128,S] bf16
__global__ __launch_bounds__(256)
void vt_cast_bf(const unsigned short* __restrict__ KV,
                unsigned short* __restrict__ VT)
{
    __shared__ unsigned short tile[32][34];
    int st = blockIdx.x * 32, dt = blockIdx.y * 32;
    int bk = blockIdx.z;
    int b = bk >> 2, kvh = bk & 3;
    int tx = threadIdx.x & 31, ty = threadIdx.x >> 5;   // 32 x 8
    #pragma unroll
    for (int i = 0; i < 32; i += 8)
        tile[ty + i][tx] = KV[(size_t)(b * Ss + st + ty + i) * 1024 + 512 + kvh * HDd + dt + tx];
    __syncthreads();
    #pragma unroll
    for (int i = 0; i < 32; i += 8)
        VT[(((size_t)b * KVHh + kvh) * HDd + dt + ty + i) * Ss + st + tx] =
            tile[tx][ty + i];
}

// Flash attention, max-free softmax (scores bounded; exp sums << fp32 range).
//
// Round-8 structure: one block = 4 waves = 4 heads of one KV group, each wave
// owning 32 q-rows (two 16-row MFMA blocks). K/V fragments are read from LDS
// ONCE per tile and feed BOTH row-blocks -> DS traffic per MFMA halves vs
// round-7. Alibi+amask+causal are folded at load time and register-prefetched
// one tile ahead (ping-pong alA/alB, static indexing) so the per-tile barrier
// (which drains vmcnt(0)) never waits on a freshly-issued HBM load — alibi was
// the dominant un-covered latency (FETCH ~93MB/dispatch = mostly alibi).
//
// Grid: 512 blocks = (pair,b:64) x (kvh:4) x (half:2); qt = half? 63-pair :
// pair, so the two blocks co-resident on a CU (i, i+256 under round-robin
// dispatch) process qt and 63-qt -> ~65 tiles/CU, balanced. 2 blocks/CU =
// 2 waves/SIMD of TLP. K LDS tile XOR-swizzled as in round-7 (verified).
__global__ __launch_bounds__(256, 2)
void flash_attn(const unsigned short* __restrict__ Qb,   // [B*S,2048] bf16
                const unsigned short* __restrict__ KVb,  // [B*S,1024] bf16 (K part)
                const unsigned short* __restrict__ VT,   // [B,KVH,128,S] bf16
                const float* __restrict__ alibi,         // [B,S,S]
                const float* __restrict__ amask,         // [B,S]
                unsigned short* __restrict__ ctx)        // [B*S,2048] bf16
{
    __shared__ __align__(16) unsigned short kbuf[2][32 * 128];  // 8KB/buf, row=key, 256B/row, swizzled
    __shared__ __align__(16) unsigned short vbuf[2][128 * 32];  // 8KB/buf, row=d, 64B/row, linear
    __shared__ unsigned short s_p[4][32][56];                    // per-wave P scratch (112B rows)

    const int tid  = threadIdx.x;
    const int w    = tid >> 6;
    const int lane = tid & 63;
    const int m    = lane & 15;
    const int quad = lane >> 4;

    const int pairIdx = blockIdx.x >> 1;        // 0..31
    const int b       = blockIdx.x & 1;
    const int kvh     = blockIdx.y;
    const int qt      = blockIdx.z ? (63 - pairIdx) : pairIdx;  // 32-row q-tile
    const int q0      = qt * 32;
    const int ntiles  = qt + 1;                 // k-tiles of 32 keys
    const int h       = kvh * 4 + w;            // this wave's head

    const unsigned short* vt0 = VT + ((size_t)b * KVHh + kvh) * HDd * Ss;
    const float* amrow = amask + (size_t)b * Ss;
    const float* arow  = alibi + ((size_t)b * Ss + q0) * Ss;
    const unsigned short* kgbase = KVb + (size_t)b * Ss * 1024 + kvh * HDd;

    // staging geometry (256 threads; DMA dest is linear in thread order)
    const int krow_s = tid >> 4;                                  // K row 0..15 (+16 on issue 1)
    const int koff_b = ((tid & 15) * 16) ^ ((krow_s & 7) << 4);   // pre-swizzled src byte in row
    const int vrow_s = tid >> 2;                                  // V row 0..63 (+64 on issue 1)
    const int vchk   = tid & 3;
    const int dstw   = w * 512;                                   // wave's 1KB stripe (ushorts)

    // Q fragments for both 16-row blocks
    bf16x8 qa[2][4];
    #pragma unroll
    for (int rb = 0; rb < 2; ++rb) {
        const unsigned short* qrow =
            Qb + (size_t)(b * Ss + q0 + rb * 16 + m) * Dd + h * HDd;
        #pragma unroll
        for (int c = 0; c < 4; ++c)
            qa[rb][c] = *reinterpret_cast<const bf16x8*>(qrow + c * 32 + quad * 8);
    }

    f32x4 o[2][8];
    #pragma unroll
    for (int rb = 0; rb < 2; ++rb)
        #pragma unroll
        for (int f = 0; f < 8; ++f) o[rb][f] = (f32x4){0.f, 0.f, 0.f, 0.f};
    float lrow[2][4] = {{0.f,0.f,0.f,0.f},{0.f,0.f,0.f,0.f}};

    float alA[2][2][4], alB[2][2][4];   // folded (alibi+amask, causal-masked)

    auto LDALIBI = [&](int k0n, float (&dst)[2][2][4]) {
        const float am0 = amrow[k0n + m];
        const float am1 = amrow[k0n + 16 + m];
        #pragma unroll
        for (int rb = 0; rb < 2; ++rb)
            #pragma unroll
            for (int r = 0; r < 4; ++r) {
                const int row = rb * 16 + quad * 4 + r;   // 0..31 within tile
                const int qi  = q0 + row;
                const float* ap = arow + (size_t)row * Ss + k0n;
                const float a0 = ap[m] + am0;
                const float a1 = ap[16 + m] + am1;
                dst[rb][0][r] = (k0n + m      <= qi) ? a0 : -1e30f;
                dst[rb][1][r] = (k0n + 16 + m <= qi) ? a1 : -1e30f;
            }
    };

    auto STAGE = [&](int kn, int buf) {
        const unsigned short* kg = kgbase + (size_t)(kn + krow_s) * 1024 + (koff_b >> 1);
        GLOAD16(kg,             &kbuf[buf][dstw]);
        GLOAD16(kg + 16 * 1024, &kbuf[buf][2048 + dstw]);
        const unsigned short* vg = vt0 + (size_t)vrow_s * Ss + kn + vchk * 8;
        GLOAD16(vg,             &vbuf[buf][dstw]);
        GLOAD16(vg + 64 * Ss,   &vbuf[buf][2048 + dstw]);
    };

    auto BODY = [&](int kt, float (&acur)[2][2][4], float (&anext)[2][2][4]) {
        const int k0  = kt * 32;
        const int cur = kt & 1;
        // prefetch tile t+1: LDS staging (async DMA) + alibi into registers
        if (kt + 1 < ntiles) {
            STAGE(k0 + 32, cur ^ 1);
            LDALIBI(k0 + 32, anext);
        }
        // K fragments (swizzled read), shared by both row-blocks
        const char* kb  = (const char*)&kbuf[cur][0];
        const int  ksw  = (m & 7) << 4;
        bf16x8 kf[2][4];
        #pragma unroll
        for (int kh = 0; kh < 2; ++kh)
            #pragma unroll
            for (int c = 0; c < 4; ++c)
                kf[kh][c] = *(const bf16x8*)(kb + (kh * 16 + m) * 256 +
                                             ((c * 64 + quad * 16) ^ ksw));
        // QK^T: 16 MFMA (2 row-blocks x 2 key-halves x 4 k-chunks)
        f32x4 s[2][2];
        s[0][0] = (f32x4){0.f,0.f,0.f,0.f}; s[0][1] = (f32x4){0.f,0.f,0.f,0.f};
        s[1][0] = (f32x4){0.f,0.f,0.f,0.f}; s[1][1] = (f32x4){0.f,0.f,0.f,0.f};
        #pragma unroll
        for (int c = 0; c < 4; ++c)
            #pragma unroll
            for (int rb = 0; rb < 2; ++rb)
                #pragma unroll
                for (int kh = 0; kh < 2; ++kh)
                    s[rb][kh] = __builtin_amdgcn_mfma_f32_16x16x32_bf16(
                        qa[rb][c], kf[kh][c], s[rb][kh], 0, 0, 0);
        // softmax: p = exp(s + folded_bias)  (mask/amask pre-folded at load)
        #pragma unroll
        for (int rb = 0; rb < 2; ++rb)
            #pragma unroll
            for (int kh = 0; kh < 2; ++kh)
                #pragma unroll
                for (int r = 0; r < 4; ++r) {
                    const float p = __expf(s[rb][kh][r] + acur[rb][kh][r]);
                    lrow[rb][r] += p;
                    s_p[w][rb * 16 + quad * 4 + r][kh * 16 + m] = f2bf(p);
                }
        // P: C-layout -> A-layout via LDS (same-wave DS is in-order)
        __builtin_amdgcn_wave_barrier();
        const bf16x8 pa0 = *reinterpret_cast<const bf16x8*>(&s_p[w][m][quad * 8]);
        const bf16x8 pa1 = *reinterpret_cast<const bf16x8*>(&s_p[w][16 + m][quad * 8]);
        __builtin_amdgcn_wave_barrier();
        // PV: V fragments read once, feed both row-blocks (16 MFMA / 8 reads)
        const char* vbp = (const char*)&vbuf[cur][0];
        #pragma unroll
        for (int f = 0; f < 8; ++f) {
            const bf16x8 vb = *(const bf16x8*)(vbp + (f * 16 + m) * 64 + quad * 16);
            o[0][f] = __builtin_amdgcn_mfma_f32_16x16x32_bf16(pa0, vb, o[0][f], 0, 0, 0);
            o[1][f] = __builtin_amdgcn_mfma_f32_16x16x32_bf16(pa1, vb, o[1][f], 0, 0, 0);
        }
        // drain stage(t+1)+alibi(t+1), sync buffer reuse (one barrier per tile)
        __syncthreads();
    };

    // prologue
    LDALIBI(0, alA);
    STAGE(0, 0);
    __syncthreads();

    int kt = 0;
    while (true) {
        BODY(kt, alA, alB); if (++kt >= ntiles) break;
        BODY(kt, alB, alA); if (++kt >= ntiles) break;
    }

    // reduce l across the 16 key-columns held by the m-lanes
    float inv[2][4];
    #pragma unroll
    for (int rb = 0; rb < 2; ++rb)
        #pragma unroll
        for (int r = 0; r < 4; ++r) {
            float l = lrow[rb][r];
            l += __shfl_xor(l, 1, 64);
            l += __shfl_xor(l, 2, 64);
            l += __shfl_xor(l, 4, 64);
            l += __shfl_xor(l, 8, 64);
            inv[rb][r] = 1.f / l;
        }
    #pragma unroll
    for (int rb = 0; rb < 2; ++rb)
        #pragma unroll
        for (int f = 0; f < 8; ++f)
            #pragma unroll
            for (int r = 0; r < 4; ++r)
                ctx[(size_t)(b * Ss + q0 + rb * 16 + quad * 4 + r) * Dd +
                    h * HDd + f * 16 + m] = f2bf(o[rb][f][r] * inv[rb][r]);
}

extern "C" void kernel_launch(void* const* d_in, const int* in_sizes, int n_in,
                              void* d_out, int out_size, void* d_ws, size_t ws_size,
                              hipStream_t stream) {
    const float* hidden = (const float*)d_in[0];
    const float* cosT   = (const float*)d_in[1];
    const float* sinT   = (const float*)d_in[2];
    const float* alibi  = (const float*)d_in[3];
    const float* amask  = (const float*)d_in[4];
    const float* wq     = (const float*)d_in[5];
    const float* wk     = (const float*)d_in[6];
    const float* wv     = (const float*)d_in[7];
    const float* wo     = (const float*)d_in[8];
    float* out = (float*)d_out;

    char* ws = (char*)d_ws;
    unsigned short* Abf   = (unsigned short*)(ws);              // 16,777,216
    unsigned short* wqT   = (unsigned short*)(ws + 16777216);   //  8,388,608
    unsigned short* kvT   = (unsigned short*)(ws + 25165824);   //  4,194,304
    unsigned short* woT   = (unsigned short*)(ws + 29360128);   //  8,388,608
    unsigned short* Qraw  = (unsigned short*)(ws + 37748736);   // 16,777,216
    unsigned short* KVraw = (unsigned short*)(ws + 54525952);   //  8,388,608
    unsigned short* VT    = (unsigned short*)(ws + 62914560);   //  4,194,304
    unsigned short* Ctx   = (unsigned short*)(ws + 67108864);   // 16,777,216
    // total: 83,886,080 B

    const int M = Bb * Ss;  // 4096

    cast_bf16<<<(M * Dd / 4) / 256, 256, 0, stream>>>(hidden, Abf);
    wt_cast<<<dim3(64, 64), 256, 0, stream>>>(wq, wqT, Dd, Dd);
    wt_cast<<<dim3(64, 16), 256, 0, stream>>>(wk, kvT, Dd, 512);
    wt_cast<<<dim3(64, 16), 256, 0, stream>>>(wv, kvT + (size_t)512 * Dd, Dd, 512);
    wt_cast<<<dim3(64, 64), 256, 0, stream>>>(wo, woT, Dd, Dd);

    gemm_bt<true><<<dim3(Dd / 128, M / 128), 256, 0, stream>>>(Abf, wqT, Qraw, M, Dd, Dd);
    gemm_bt<true><<<dim3(1024 / 128, M / 128), 256, 0, stream>>>(Abf, kvT, KVraw, M, 1024, Dd);

    const float scale = 0.08838834764831845f;  // 1/sqrt(128), folded into Q
    int totQ = Bb * Ss * Hh * 64;
    rope_bf<<<totQ / 256, 256, 0, stream>>>(Qraw, cosT, sinT, 4, Dd, scale, totQ);
    int totK = Bb * Ss * KVHh * 64;
    rope_bf<<<totK / 256, 256, 0, stream>>>(KVraw, cosT, sinT, 2, 1024, 1.0f, totK);

    vt_cast_bf<<<dim3(Ss / 32, HDd / 32, Bb * KVHh), 256, 0, stream>>>(KVraw, VT);

    flash_attn<<<dim3(64, KVHh, 2), 256, 0, stream>>>(Qraw, KVraw, VT, alibi, amask, Ctx);

    gemm_bt<false><<<dim3(Dd / 128, M / 128), 256, 0, stream>>>(Ctx, woT, out, M, Dd, Dd);
}

// Round 4
// 420.507 us; speedup vs baseline: 1.1370x; 1.1370x over previous
//
#include <hip/hip_runtime.h>
#include <hip/hip_bf16.h>

#define Bb   2
#define Ss   2048
#define Dd   2048
#define Hh   16
#define KVHh 4
#define HDd  128

typedef __bf16 bf16x8 __attribute__((ext_vector_type(8)));
typedef float f32x4 __attribute__((ext_vector_type(4)));

__device__ __forceinline__ unsigned short f2bf(float f) {
    unsigned u = __float_as_uint(f);
    unsigned r = (u + 0x7FFFu + ((u >> 16) & 1u)) >> 16;   // RNE
    return (unsigned short)r;
}
__device__ __forceinline__ float bfu2f(unsigned short u) {
    return __uint_as_float(((unsigned)u) << 16);
}

// async global->LDS, 16B per lane; lds base must be wave-uniform (HW adds lane*16)
#define GLOAD16(g, l) __builtin_amdgcn_global_load_lds( \
    (const __attribute__((address_space(1))) unsigned int*)(g), \
    (__attribute__((address_space(3))) unsigned int*)(l), 16, 0, 0)

// fp32 -> bf16 elementwise, 4 elems/thread
__global__ __launch_bounds__(256)
void cast_bf16(const float* __restrict__ X, unsigned short* __restrict__ Y)
{
    int idx = blockIdx.x * 256 + threadIdx.x;
    float4 v = reinterpret_cast<const float4*>(X)[idx];
    ushort4 o;
    o.x = f2bf(v.x); o.y = f2bf(v.y); o.z = f2bf(v.z); o.w = f2bf(v.w);
    reinterpret_cast<ushort4*>(Y)[idx] = o;
}

// W[K,N] fp32 -> WT[N,K] bf16
__global__ __launch_bounds__(256)
void wt_cast(const float* __restrict__ W, unsigned short* __restrict__ WT,
             int K, int N)
{
    __shared__ float tile[32][33];
    int k0 = blockIdx.x * 32, n0 = blockIdx.y * 32;
    int tx = threadIdx.x & 31, ty = threadIdx.x >> 5;   // 32 x 8
    #pragma unroll
    for (int i = 0; i < 32; i += 8)
        tile[ty + i][tx] = W[(size_t)(k0 + ty + i) * N + n0 + tx];
    __syncthreads();
    #pragma unroll
    for (int i = 0; i < 32; i += 8)
        WT[(size_t)(n0 + ty + i) * K + k0 + tx] = f2bf(tile[tx][ty + i]);
}

// C[M,N] = A[M,K] @ BT[N,K]^T, bf16 in, fp32 accumulate, fp32 or bf16 out.
// 128x128 tile, BK=32, 4 waves (2x2 of 64x64), global_load_lds staging.
template<bool BF16OUT>
__global__ __launch_bounds__(256)
void gemm_bt(const unsigned short* __restrict__ A,
             const unsigned short* __restrict__ BT,
             void* __restrict__ Cv, int M, int N, int K)
{
    __shared__ __align__(16) unsigned short sA[128 * 32];
    __shared__ __align__(16) unsigned short sB[128 * 32];
    const int tid  = threadIdx.x;
    const int wave = tid >> 6;
    const int lane = tid & 63;
    const int m    = lane & 15;
    const int quad = lane >> 4;
    const int wm   = wave >> 1, wn = wave & 1;
    const int m0   = blockIdx.y * 128, n0 = blockIdx.x * 128;

    const int srow = tid >> 2;          // 0..63
    const int skg  = (tid & 3) * 8;     // k-group *8 elems

    f32x4 acc[4][4];
    #pragma unroll
    for (int r = 0; r < 4; ++r)
        #pragma unroll
        for (int c = 0; c < 4; ++c) acc[r][c] = (f32x4){0.f, 0.f, 0.f, 0.f};

    const unsigned short* pa = A  + (size_t)(m0 + srow) * K + skg;
    const unsigned short* pb = BT + (size_t)(n0 + srow) * K + skg;
    unsigned short* la = &sA[wave * 16 * 32];   // wave-uniform LDS base
    unsigned short* lb = &sB[wave * 16 * 32];

    for (int k0 = 0; k0 < K; k0 += 32) {
        GLOAD16(pa + k0, la);
        GLOAD16(pa + (size_t)64 * K + k0, la + 64 * 32);
        GLOAD16(pb + k0, lb);
        GLOAD16(pb + (size_t)64 * K + k0, lb + 64 * 32);
        __syncthreads();
        bf16x8 af[4], bfr[4];
        #pragma unroll
        for (int r = 0; r < 4; ++r)
            af[r] = *reinterpret_cast<const bf16x8*>(
                &sA[(wm * 64 + r * 16 + m) * 32 + quad * 8]);
        #pragma unroll
        for (int c = 0; c < 4; ++c)
            bfr[c] = *reinterpret_cast<const bf16x8*>(
                &sB[(wn * 64 + c * 16 + m) * 32 + quad * 8]);
        #pragma unroll
        for (int r = 0; r < 4; ++r)
            #pragma unroll
            for (int c = 0; c < 4; ++c)
                acc[r][c] = __builtin_amdgcn_mfma_f32_16x16x32_bf16(
                    af[r], bfr[c], acc[r][c], 0, 0, 0);
        __syncthreads();
    }
    // C/D layout: row = quad*4 + e, col = m
    #pragma unroll
    for (int r = 0; r < 4; ++r)
        #pragma unroll
        for (int c = 0; c < 4; ++c)
            #pragma unroll
            for (int e = 0; e < 4; ++e) {
                size_t row = m0 + wm * 64 + r * 16 + quad * 4 + e;
                size_t col = n0 + wn * 64 + c * 16 + m;
                if (BF16OUT)
                    ((unsigned short*)Cv)[row * N + col] = f2bf(acc[r][c][e]);
                else
                    ((float*)Cv)[row * N + col] = acc[r][c][e];
            }
}

// In-place RoPE on bf16 X, rows of `rowstride`, head slice h*128.
__global__ __launch_bounds__(256)
void rope_bf(unsigned short* __restrict__ X, const float* __restrict__ cosT,
             const float* __restrict__ sinT, int nhshift, int rowstride,
             float scale, int total)
{
    int idx = blockIdx.x * 256 + threadIdx.x;
    if (idx >= total) return;
    int i   = idx & 63;
    int rh  = idx >> 6;                  // (b*S+s)*nh + h
    int row = rh >> nhshift;             // b*S + s
    int h   = rh & ((1 << nhshift) - 1);
    int s   = row & (Ss - 1);
    unsigned short* xp = X + (size_t)row * rowstride + h * HDd;
    float x1 = bfu2f(xp[i]);
    float x2 = bfu2f(xp[i + 64]);
    float c1 = cosT[s * HDd + i];
    float c2 = cosT[s * HDd + i + 64];
    float s1 = sinT[s * HDd + i];
    float s2 = sinT[s * HDd + i + 64];
    xp[i]      = f2bf((x1 * c1 - x2 * s1) * scale);
    xp[i + 64] = f2bf((x2 * c2 + x1 * s2) * scale);
}

// V (cols 512.. of KVraw [B*S,1024] bf16) -> VT [B,KVH,128,S] bf16
__global__ __launch_bounds__(256)
void vt_cast_bf(const unsigned short* __restrict__ KV,
                unsigned short* __restrict__ VT)
{
    __shared__ unsigned short tile[32][34];
    int st = blockIdx.x * 32, dt = blockIdx.y * 32;
    int bk = blockIdx.z;
    int b = bk >> 2, kvh = bk & 3;
    int tx = threadIdx.x & 31, ty = threadIdx.x >> 5;   // 32 x 8
    #pragma unroll
    for (int i = 0; i < 32; i += 8)
        tile[ty + i][tx] = KV[(size_t)(b * Ss + st + ty + i) * 1024 + 512 + kvh * HDd + dt + tx];
    __syncthreads();
    #pragma unroll
    for (int i = 0; i < 32; i += 8)
        VT[(((size_t)b * KVHh + kvh) * HDd + dt + ty + i) * Ss + st + tx] =
            tile[tx][ty + i];
}

// Flash attention, max-free softmax (scores bounded; exp sums << fp32 range).
//
// Round-9 = round-7 structure (verified 117.5us: one block = 4 waves = 4
// heads of one KV group, internal balanced pair {qt,127-qt}, K/V in
// double-buffered LDS via global_load_lds) + two measured fixes:
//
// 1. V-read was an 8-way bank conflict (9.05M conflict cycles): consecutive
//    8-lane groups hit 2 of 8 16B windows. Fix: XOR-swizzle
//    byte ^= ((row>>1)&3)<<4, both-sides (pre-swizzled GLOBAL source chunk
//    since global_load_lds writes linearly; swizzled read offset).
//    Enumerated: every 8-lane group now covers all 8 windows.
// 2. Alibi (33MB, streamed once -> always HBM-miss ~900cyc) was loaded
//    per-lane inside the tile, stalling softmax. Now staged into LDS
//    (2KB/tile, tid<128 x one GLOAD16) one tile ahead with K/V, drained by
//    the same per-tile barrier. Zero VGPR cost, cannot be sunk by the
//    scheduler. Causal+amask fold back into softmax VALU.
__global__ __launch_bounds__(256, 2)
void flash_attn(const unsigned short* __restrict__ Qb,   // [B*S,2048] bf16
                const unsigned short* __restrict__ KVb,  // [B*S,1024] bf16 (K part)
                const unsigned short* __restrict__ VT,   // [B,KVH,128,S] bf16
                const float* __restrict__ alibi,         // [B,S,S]
                const float* __restrict__ amask,         // [B,S]
                unsigned short* __restrict__ ctx)        // [B*S,2048] bf16
{
    __shared__ __align__(16) unsigned short kbuf[2][32 * 128];  // 8KB/buf, row=key, 256B/row, swizzled
    __shared__ __align__(16) unsigned short vbuf[2][128 * 32];  // 8KB/buf, row=d, 64B/row, swizzled
    __shared__ __align__(16) float          abuf[2][16 * 32];   // 2KB/buf, alibi slab [qrow][key]
    __shared__ unsigned short s_p[4][16][56];                    // per-wave P scratch (112B rows)

    const int tid  = threadIdx.x;
    const int w    = tid >> 6;
    const int lane = tid & 63;
    const int m    = lane & 15;
    const int quad = lane >> 4;

    const int kvh = blockIdx.y;
    const int b   = blockIdx.z;
    const int h   = kvh * 4 + w;        // this wave's head

    const unsigned short* vt0 = VT + ((size_t)b * KVHh + kvh) * HDd * Ss;
    const float* amrow = amask + (size_t)b * Ss;

    // staging geometry (256 threads; DMA dest is linear in thread order)
    const int krow_s = tid >> 4;                                  // K row 0..15 (+16 on issue 1)
    const int koff_b = ((tid & 15) * 16) ^ ((krow_s & 7) << 4);   // pre-swizzled src byte in row
    const int vrow_s = tid >> 2;                                  // V row 0..63 (+64 on issue 1)
    const int vchk_s = (tid & 3) ^ ((vrow_s >> 1) & 3);           // pre-swizzled src 16B chunk
    const int dstw   = w * 512;                                   // wave's 1KB stripe (ushorts)
    // note: (row+16)&7 == row&7 and ((row+64)>>1)&3 == (row>>1)&3, so the
    // same swizzle applies to both issues of each operand.

    const unsigned short* kgbase = KVb + (size_t)b * Ss * 1024 + kvh * HDd;

    const int qts[2] = { (int)blockIdx.x, 127 - (int)blockIdx.x };

    #pragma unroll 1
    for (int pi = 0; pi < 2; ++pi) {
        const int q0 = qts[pi] * 16;

        bf16x8 qa[4];
        {
            const unsigned short* qrow = Qb + (size_t)(b * Ss + q0 + m) * Dd + h * HDd;
            #pragma unroll
            for (int c = 0; c < 4; ++c)
                qa[c] = *reinterpret_cast<const bf16x8*>(qrow + c * 32 + quad * 8);
        }

        f32x4 o[8];
        #pragma unroll
        for (int f = 0; f < 8; ++f) o[f] = (f32x4){0.f, 0.f, 0.f, 0.f};
        float lrow[4] = {0.f, 0.f, 0.f, 0.f};

        const float* arowB = alibi + ((size_t)b * Ss + q0) * Ss;   // block-level alibi base
        const int ntiles = (q0 + 47) >> 5;      // keys 0..q0+15 (>= 1)

        // stage K/V/alibi for tile starting at key kn into buffer buf
        auto STAGE = [&](int kn, int buf) {
            const unsigned short* kg =
                kgbase + (size_t)(kn + krow_s) * 1024 + (koff_b >> 1);
            GLOAD16(kg,             &kbuf[buf][dstw]);
            GLOAD16(kg + 16 * 1024, &kbuf[buf][2048 + dstw]);
            const unsigned short* vg = vt0 + (size_t)vrow_s * Ss + kn + vchk_s * 8;
            GLOAD16(vg,             &vbuf[buf][dstw]);
            GLOAD16(vg + 64 * Ss,   &vbuf[buf][2048 + dstw]);
            if (tid < 128) {       // 16 rows x 128B of alibi, linear dest
                const float* ag = arowB + (size_t)(tid >> 3) * Ss + kn + (tid & 7) * 4;
                GLOAD16(ag, &abuf[buf][w * 256]);
            }
        };

        // prologue: stage tile 0 into buf 0
        STAGE(0, 0);
        __syncthreads();

        #pragma unroll 1
        for (int kt = 0; kt < ntiles; ++kt) {
            const int k0  = kt * 32;
            const int cur = kt & 1;

            // --- stage tile t+1 into the other buffer (async, no regs) ---
            if (kt + 1 < ntiles) STAGE(k0 + 32, cur ^ 1);

            // --- amask (tiny, L2-hot; covered by QK) ---
            const float am0 = amrow[k0 + m];
            const float am1 = amrow[k0 + 16 + m];

            // --- K fragments from LDS (swizzled read) + QK^T ---
            const char* kb  = (const char*)&kbuf[cur][0];
            const char* vbp = (const char*)&vbuf[cur][0];
            const int  ksw  = (m & 7) << 4;
            const int  vsw  = ((m >> 1) & 3) << 4;
            bf16x8 kb0[4], kb1[4];
            #pragma unroll
            for (int c = 0; c < 4; ++c) {
                kb0[c] = *(const bf16x8*)(kb + m * 256        + ((c * 64 + quad * 16) ^ ksw));
                kb1[c] = *(const bf16x8*)(kb + (16 + m) * 256 + ((c * 64 + quad * 16) ^ ksw));
            }
            f32x4 s0 = {0.f, 0.f, 0.f, 0.f}, s1 = {0.f, 0.f, 0.f, 0.f};
            #pragma unroll
            for (int c = 0; c < 4; ++c) {
                s0 = __builtin_amdgcn_mfma_f32_16x16x32_bf16(qa[c], kb0[c], s0, 0, 0, 0);
                s1 = __builtin_amdgcn_mfma_f32_16x16x32_bf16(qa[c], kb1[c], s1, 0, 0, 0);
            }

            // --- max-free softmax: p = exp(s + alibi + amask), causal-masked ---
            #pragma unroll
            for (int r = 0; r < 4; ++r) {
                const int row = quad * 4 + r;
                const int qi  = q0 + row;
                float x0 = s0[r] + abuf[cur][row * 32 + m]      + am0;
                float x1 = s1[r] + abuf[cur][row * 32 + 16 + m] + am1;
                x0 = (k0 + m      <= qi) ? x0 : -1e30f;
                x1 = (k0 + 16 + m <= qi) ? x1 : -1e30f;
                const float p0 = __expf(x0);
                const float p1 = __expf(x1);
                lrow[r] += p0 + p1;
                s_p[w][row][m]      = f2bf(p0);
                s_p[w][row][16 + m] = f2bf(p1);
            }
            // P: C-layout -> A-layout via LDS (same-wave DS is in-order)
            __builtin_amdgcn_wave_barrier();
            const bf16x8 pa = *reinterpret_cast<const bf16x8*>(&s_p[w][m][quad * 8]);
            __builtin_amdgcn_wave_barrier();

            // --- PV from LDS V (swizzled read, conflict-free) ---
            #pragma unroll
            for (int f = 0; f < 8; ++f) {
                const bf16x8 vb = *(const bf16x8*)(vbp + (f * 16 + m) * 64 +
                                                   ((quad * 16) ^ vsw));
                o[f] = __builtin_amdgcn_mfma_f32_16x16x32_bf16(pa, vb, o[f], 0, 0, 0);
            }

            // drain stage(t+1) + sync buffer reuse (one barrier per tile)
            __syncthreads();
        }

        // reduce l across the 16 columns held by lanes of each quad-row group
        float inv[4];
        #pragma unroll
        for (int r = 0; r < 4; ++r) {
            float l = lrow[r];
            l += __shfl_xor(l, 1, 64);
            l += __shfl_xor(l, 2, 64);
            l += __shfl_xor(l, 4, 64);
            l += __shfl_xor(l, 8, 64);
            inv[r] = 1.f / l;
        }
        #pragma unroll
        for (int f = 0; f < 8; ++f)
            #pragma unroll
            for (int r = 0; r < 4; ++r)
                ctx[(size_t)(b * Ss + q0 + quad * 4 + r) * Dd + h * HDd + f * 16 + m] =
                    f2bf(o[f][r] * inv[r]);
    }
}

extern "C" void kernel_launch(void* const* d_in, const int* in_sizes, int n_in,
                              void* d_out, int out_size, void* d_ws, size_t ws_size,
                              hipStream_t stream) {
    const float* hidden = (const float*)d_in[0];
    const float* cosT   = (const float*)d_in[1];
    const float* sinT   = (const float*)d_in[2];
    const float* alibi  = (const float*)d_in[3];
    const float* amask  = (const float*)d_in[4];
    const float* wq     = (const float*)d_in[5];
    const float* wk     = (const float*)d_in[6];
    const float* wv     = (const float*)d_in[7];
    const float* wo     = (const float*)d_in[8];
    float* out = (float*)d_out;

    char* ws = (char*)d_ws;
    unsigned short* Abf   = (unsigned short*)(ws);              // 16,777,216
    unsigned short* wqT   = (unsigned short*)(ws + 16777216);   //  8,388,608
    unsigned short* kvT   = (unsigned short*)(ws + 25165824);   //  4,194,304
    unsigned short* woT   = (unsigned short*)(ws + 29360128);   //  8,388,608
    unsigned short* Qraw  = (unsigned short*)(ws + 37748736);   // 16,777,216
    unsigned short* KVraw = (unsigned short*)(ws + 54525952);   //  8,388,608
    unsigned short* VT    = (unsigned short*)(ws + 62914560);   //  4,194,304
    unsigned short* Ctx   = (unsigned short*)(ws + 67108864);   // 16,777,216
    // total: 83,886,080 B

    const int M = Bb * Ss;  // 4096

    cast_bf16<<<(M * Dd / 4) / 256, 256, 0, stream>>>(hidden, Abf);
    wt_cast<<<dim3(64, 64), 256, 0, stream>>>(wq, wqT, Dd, Dd);
    wt_cast<<<dim3(64, 16), 256, 0, stream>>>(wk, kvT, Dd, 512);
    wt_cast<<<dim3(64, 16), 256, 0, stream>>>(wv, kvT + (size_t)512 * Dd, Dd, 512);
    wt_cast<<<dim3(64, 64), 256, 0, stream>>>(wo, woT, Dd, Dd);

    gemm_bt<true><<<dim3(Dd / 128, M / 128), 256, 0, stream>>>(Abf, wqT, Qraw, M, Dd, Dd);
    gemm_bt<true><<<dim3(1024 / 128, M / 128), 256, 0, stream>>>(Abf, kvT, KVraw, M, 1024, Dd);

    const float scale = 0.08838834764831845f;  // 1/sqrt(128), folded into Q
    int totQ = Bb * Ss * Hh * 64;
    rope_bf<<<totQ / 256, 256, 0, stream>>>(Qraw, cosT, sinT, 4, Dd, scale, totQ);
    int totK = Bb * Ss * KVHh * 64;
    rope_bf<<<totK / 256, 256, 0, stream>>>(KVraw, cosT, sinT, 2, 1024, 1.0f, totK);

    vt_cast_bf<<<dim3(Ss / 32, HDd / 32, Bb * KVHh), 256, 0, stream>>>(KVraw, VT);

    flash_attn<<<dim3(64, KVHh, Bb), 256, 0, stream>>>(Qraw, KVraw, VT, alibi, amask, Ctx);

    gemm_bt<false><<<dim3(Dd / 128, M / 128), 256, 0, stream>>>(Ctx, woT, out, M, Dd, Dd);
}

// Round 5
// 417.399 us; speedup vs baseline: 1.1454x; 1.0074x over previous
//
#include <hip/hip_runtime.h>
#include <hip/hip_bf16.h>

#define Bb   2
#define Ss   2048
#define Dd   2048
#define Hh   16
#define KVHh 4
#define HDd  128

typedef __bf16 bf16x8 __attribute__((ext_vector_type(8)));
typedef float f32x4 __attribute__((ext_vector_type(4)));

__device__ __forceinline__ unsigned short f2bf(float f) {
    unsigned u = __float_as_uint(f);
    unsigned r = (u + 0x7FFFu + ((u >> 16) & 1u)) >> 16;   // RNE
    return (unsigned short)r;
}
__device__ __forceinline__ float bfu2f(unsigned short u) {
    return __uint_as_float(((unsigned)u) << 16);
}

// async global->LDS, 16B per lane; lds base must be wave-uniform (HW adds lane*16)
#define GLOAD16(g, l) __builtin_amdgcn_global_load_lds( \
    (const __attribute__((address_space(1))) unsigned int*)(g), \
    (__attribute__((address_space(3))) unsigned int*)(l), 16, 0, 0)

// fp32 -> bf16 elementwise, 4 elems/thread
__global__ __launch_bounds__(256)
void cast_bf16(const float* __restrict__ X, unsigned short* __restrict__ Y)
{
    int idx = blockIdx.x * 256 + threadIdx.x;
    float4 v = reinterpret_cast<const float4*>(X)[idx];
    ushort4 o;
    o.x = f2bf(v.x); o.y = f2bf(v.y); o.z = f2bf(v.z); o.w = f2bf(v.w);
    reinterpret_cast<ushort4*>(Y)[idx] = o;
}

// W[K,N] fp32 -> WT[N,K] bf16
__global__ __launch_bounds__(256)
void wt_cast(const float* __restrict__ W, unsigned short* __restrict__ WT,
             int K, int N)
{
    __shared__ float tile[32][33];
    int k0 = blockIdx.x * 32, n0 = blockIdx.y * 32;
    int tx = threadIdx.x & 31, ty = threadIdx.x >> 5;   // 32 x 8
    #pragma unroll
    for (int i = 0; i < 32; i += 8)
        tile[ty + i][tx] = W[(size_t)(k0 + ty + i) * N + n0 + tx];
    __syncthreads();
    #pragma unroll
    for (int i = 0; i < 32; i += 8)
        WT[(size_t)(n0 + ty + i) * K + k0 + tx] = f2bf(tile[tx][ty + i]);
}

// C[M,N] = A[M,K] @ BT[N,K]^T, bf16 in, fp32 accumulate, fp32 or bf16 out.
// 128x128 tile, BK=32, 4 waves (2x2 of 64x64), global_load_lds staging.
template<bool BF16OUT>
__global__ __launch_bounds__(256)
void gemm_bt(const unsigned short* __restrict__ A,
             const unsigned short* __restrict__ BT,
             void* __restrict__ Cv, int M, int N, int K)
{
    __shared__ __align__(16) unsigned short sA[128 * 32];
    __shared__ __align__(16) unsigned short sB[128 * 32];
    const int tid  = threadIdx.x;
    const int wave = tid >> 6;
    const int lane = tid & 63;
    const int m    = lane & 15;
    const int quad = lane >> 4;
    const int wm   = wave >> 1, wn = wave & 1;
    const int m0   = blockIdx.y * 128, n0 = blockIdx.x * 128;

    const int srow = tid >> 2;          // 0..63
    const int skg  = (tid & 3) * 8;     // k-group *8 elems

    f32x4 acc[4][4];
    #pragma unroll
    for (int r = 0; r < 4; ++r)
        #pragma unroll
        for (int c = 0; c < 4; ++c) acc[r][c] = (f32x4){0.f, 0.f, 0.f, 0.f};

    const unsigned short* pa = A  + (size_t)(m0 + srow) * K + skg;
    const unsigned short* pb = BT + (size_t)(n0 + srow) * K + skg;
    unsigned short* la = &sA[wave * 16 * 32];   // wave-uniform LDS base
    unsigned short* lb = &sB[wave * 16 * 32];

    for (int k0 = 0; k0 < K; k0 += 32) {
        GLOAD16(pa + k0, la);
        GLOAD16(pa + (size_t)64 * K + k0, la + 64 * 32);
        GLOAD16(pb + k0, lb);
        GLOAD16(pb + (size_t)64 * K + k0, lb + 64 * 32);
        __syncthreads();
        bf16x8 af[4], bfr[4];
        #pragma unroll
        for (int r = 0; r < 4; ++r)
            af[r] = *reinterpret_cast<const bf16x8*>(
                &sA[(wm * 64 + r * 16 + m) * 32 + quad * 8]);
        #pragma unroll
        for (int c = 0; c < 4; ++c)
            bfr[c] = *reinterpret_cast<const bf16x8*>(
                &sB[(wn * 64 + c * 16 + m) * 32 + quad * 8]);
        #pragma unroll
        for (int r = 0; r < 4; ++r)
            #pragma unroll
            for (int c = 0; c < 4; ++c)
                acc[r][c] = __builtin_amdgcn_mfma_f32_16x16x32_bf16(
                    af[r], bfr[c], acc[r][c], 0, 0, 0);
        __syncthreads();
    }
    // C/D layout: row = quad*4 + e, col = m
    #pragma unroll
    for (int r = 0; r < 4; ++r)
        #pragma unroll
        for (int c = 0; c < 4; ++c)
            #pragma unroll
            for (int e = 0; e < 4; ++e) {
                size_t row = m0 + wm * 64 + r * 16 + quad * 4 + e;
                size_t col = n0 + wn * 64 + c * 16 + m;
                if (BF16OUT)
                    ((unsigned short*)Cv)[row * N + col] = f2bf(acc[r][c][e]);
                else
                    ((float*)Cv)[row * N + col] = acc[r][c][e];
            }
}

// In-place RoPE on bf16 X, rows of `rowstride`, head slice h*128.
__global__ __launch_bounds__(256)
void rope_bf(unsigned short* __restrict__ X, const float* __restrict__ cosT,
             const float* __restrict__ sinT, int nhshift, int rowstride,
             float scale, int total)
{
    int idx = blockIdx.x * 256 + threadIdx.x;
    if (idx >= total) return;
    int i   = idx & 63;
    int rh  = idx >> 6;                  // (b*S+s)*nh + h
    int row = rh >> nhshift;             // b*S + s
    int h   = rh & ((1 << nhshift) - 1);
    int s   = row & (Ss - 1);
    unsigned short* xp = X + (size_t)row * rowstride + h * HDd;
    float x1 = bfu2f(xp[i]);
    float x2 = bfu2f(xp[i + 64]);
    float c1 = cosT[s * HDd + i];
    float c2 = cosT[s * HDd + i + 64];
    float s1 = sinT[s * HDd + i];
    float s2 = sinT[s * HDd + i + 64];
    xp[i]      = f2bf((x1 * c1 - x2 * s1) * scale);
    xp[i + 64] = f2bf((x2 * c2 + x1 * s2) * scale);
}

// V (cols 512.. of KVraw [B*S,1024] bf16) -> VT [B,KVH,128,S] bf16
__global__ __launch_bounds__(256)
void vt_cast_bf(const unsigned short* __restrict__ KV,
                unsigned short* __restrict__ VT)
{
    __shared__ unsigned short tile[32][34];
    int st = blockIdx.x * 32, dt = blockIdx.y * 32;
    int bk = blockIdx.z;
    int b = bk >> 2, kvh = bk & 3;
    int tx = threadIdx.x & 31, ty = threadIdx.x >> 5;   // 32 x 8
    #pragma unroll
    for (int i = 0; i < 32; i += 8)
        tile[ty + i][tx] = KV[(size_t)(b * Ss + st + ty + i) * 1024 + 512 + kvh * HDd + dt + tx];
    __syncthreads();
    #pragma unroll
    for (int i = 0; i < 32; i += 8)
        VT[(((size_t)b * KVHh + kvh) * HDd + dt + ty + i) * Ss + st + tx] =
            tile[tx][ty + i];
}

// Flash attention, max-free softmax (scores bounded; exp sums << fp32 range).
//
// Round-10 = round-9 + counted-vmcnt pipeline (T4):
// __syncthreads() drains vmcnt(0), i.e. every tile waited for its OWN
// just-issued prefetch (~900cyc alibi HBM miss > ~600cyc compute cover).
// Now: triple-buffered K/V/alibi, ONE raw s_barrier per tile, and an
// inline-asm counted wait (vmcnt(5) for waves 0-1 which also stage alibi,
// vmcnt(4) for waves 2-3) so stage(t+1) stays IN FLIGHT across the barrier;
// FIFO vmcnt semantics mean <=5 outstanding == stage(t) complete.
// Triple-buffering makes the DMA-written buffer 2 tiles away from any
// reader, so the per-tile read-protection barrier can be dropped.
// amask is hoisted to LDS once per block: the loop body must contain ZERO
// compiler-managed vector loads, else the compiler's inserted wait for them
// would (FIFO) drain our prefetch too. sched_barrier(0) after the raw
// barrier pins ds_reads (raw s_barrier is not an LLVM memory fence).
__global__ __launch_bounds__(256, 2)
void flash_attn(const unsigned short* __restrict__ Qb,   // [B*S,2048] bf16
                const unsigned short* __restrict__ KVb,  // [B*S,1024] bf16 (K part)
                const unsigned short* __restrict__ VT,   // [B,KVH,128,S] bf16
                const float* __restrict__ alibi,         // [B,S,S]
                const float* __restrict__ amask,         // [B,S]
                unsigned short* __restrict__ ctx)        // [B*S,2048] bf16
{
    __shared__ __align__(16) unsigned short kbuf[3][32 * 128];  // 8KB/buf, row=key, 256B/row, swizzled
    __shared__ __align__(16) unsigned short vbuf[3][128 * 32];  // 8KB/buf, row=d, 64B/row, swizzled
    __shared__ __align__(16) float          abuf[3][16 * 32];   // 2KB/buf, alibi slab [qrow][key]
    __shared__ __align__(16) float          am_lds[Ss];         // 8KB, amask row for this b
    __shared__ unsigned short s_p[4][16][56];                    // per-wave P scratch (112B rows)

    const int tid  = threadIdx.x;
    const int w    = tid >> 6;
    const int lane = tid & 63;
    const int m    = lane & 15;
    const int quad = lane >> 4;

    const int kvh = blockIdx.y;
    const int b   = blockIdx.z;
    const int h   = kvh * 4 + w;        // this wave's head

    const unsigned short* vt0 = VT + ((size_t)b * KVHh + kvh) * HDd * Ss;
    const float* amrow = amask + (size_t)b * Ss;

    // staging geometry (256 threads; DMA dest is linear in thread order)
    const int krow_s = tid >> 4;                                  // K row 0..15 (+16 on issue 1)
    const int koff_b = ((tid & 15) * 16) ^ ((krow_s & 7) << 4);   // pre-swizzled src byte in row
    const int vrow_s = tid >> 2;                                  // V row 0..63 (+64 on issue 1)
    const int vchk_s = (tid & 3) ^ ((vrow_s >> 1) & 3);           // pre-swizzled src 16B chunk
    const int dstw   = w * 512;                                   // wave's 1KB stripe (ushorts)

    const unsigned short* kgbase = KVb + (size_t)b * Ss * 1024 + kvh * HDd;

    // ---- block prologue: amask row -> LDS once (2 x 4KB issues) ----
    {
        const float* ag = amrow + tid * 4;
        GLOAD16(ag,        am_lds + w * 256);
        GLOAD16(ag + 1024, am_lds + 1024 + w * 256);
    }

    const int qts[2] = { (int)blockIdx.x, 127 - (int)blockIdx.x };

    #pragma unroll 1
    for (int pi = 0; pi < 2; ++pi) {
        const int q0 = qts[pi] * 16;

        bf16x8 qa[4];
        {
            const unsigned short* qrow = Qb + (size_t)(b * Ss + q0 + m) * Dd + h * HDd;
            #pragma unroll
            for (int c = 0; c < 4; ++c)
                qa[c] = *reinterpret_cast<const bf16x8*>(qrow + c * 32 + quad * 8);
        }

        f32x4 o[8];
        #pragma unroll
        for (int f = 0; f < 8; ++f) o[f] = (f32x4){0.f, 0.f, 0.f, 0.f};
        float lrow[4] = {0.f, 0.f, 0.f, 0.f};

        const float* arowB = alibi + ((size_t)b * Ss + q0) * Ss;   // block-level alibi base
        const int ntiles = (q0 + 47) >> 5;      // keys 0..q0+15 (>= 1)

        // stage K/V/alibi for tile starting at key kn into buffer buf
        auto STAGE = [&](int kn, int buf) {
            const unsigned short* kg =
                kgbase + (size_t)(kn + krow_s) * 1024 + (koff_b >> 1);
            GLOAD16(kg,             &kbuf[buf][dstw]);
            GLOAD16(kg + 16 * 1024, &kbuf[buf][2048 + dstw]);
            const unsigned short* vg = vt0 + (size_t)vrow_s * Ss + kn + vchk_s * 8;
            GLOAD16(vg,             &vbuf[buf][dstw]);
            GLOAD16(vg + 64 * Ss,   &vbuf[buf][2048 + dstw]);
            if (tid < 128) {       // 16 rows x 128B of alibi, linear dest
                const float* ag = arowB + (size_t)(tid >> 3) * Ss + kn + (tid & 7) * 4;
                GLOAD16(ag, &abuf[buf][w * 256]);
            }
        };

        // prologue: stage tile 0 into buf 0, full drain (also covers amask/Q)
        STAGE(0, 0);
        asm volatile("s_waitcnt vmcnt(0)" ::: "memory");
        __syncthreads();

        int cur = 0;
        #pragma unroll 1
        for (int kt = 0; kt < ntiles; ++kt) {
            const int k0  = kt * 32;
            const int nxt = (cur == 2) ? 0 : cur + 1;

            // stage t+1, then counted wait: <=5(4) outstanding == stage(t) done
            if (kt + 1 < ntiles) {
                STAGE(k0 + 32, nxt);
                if (w < 2) asm volatile("s_waitcnt vmcnt(5)" ::: "memory");
                else       asm volatile("s_waitcnt vmcnt(4)" ::: "memory");
            } else {
                asm volatile("s_waitcnt vmcnt(0)" ::: "memory");
            }
            __builtin_amdgcn_s_barrier();        // raw: does NOT drain vmcnt
            __builtin_amdgcn_sched_barrier(0);   // pin: no ds_read hoisted above

            // --- amask from LDS (tiny) ---
            const float am0 = am_lds[k0 + m];
            const float am1 = am_lds[k0 + 16 + m];

            // --- K fragments from LDS (swizzled read) + QK^T ---
            const char* kb  = (const char*)&kbuf[cur][0];
            const char* vbp = (const char*)&vbuf[cur][0];
            const int  ksw  = (m & 7) << 4;
            const int  vsw  = ((m >> 1) & 3) << 4;
            bf16x8 kb0[4], kb1[4];
            #pragma unroll
            for (int c = 0; c < 4; ++c) {
                kb0[c] = *(const bf16x8*)(kb + m * 256        + ((c * 64 + quad * 16) ^ ksw));
                kb1[c] = *(const bf16x8*)(kb + (16 + m) * 256 + ((c * 64 + quad * 16) ^ ksw));
            }
            f32x4 s0 = {0.f, 0.f, 0.f, 0.f}, s1 = {0.f, 0.f, 0.f, 0.f};
            #pragma unroll
            for (int c = 0; c < 4; ++c) {
                s0 = __builtin_amdgcn_mfma_f32_16x16x32_bf16(qa[c], kb0[c], s0, 0, 0, 0);
                s1 = __builtin_amdgcn_mfma_f32_16x16x32_bf16(qa[c], kb1[c], s1, 0, 0, 0);
            }

            // --- max-free softmax: p = exp(s + alibi + amask), causal-masked ---
            #pragma unroll
            for (int r = 0; r < 4; ++r) {
                const int row = quad * 4 + r;
                const int qi  = q0 + row;
                float x0 = s0[r] + abuf[cur][row * 32 + m]      + am0;
                float x1 = s1[r] + abuf[cur][row * 32 + 16 + m] + am1;
                x0 = (k0 + m      <= qi) ? x0 : -1e30f;
                x1 = (k0 + 16 + m <= qi) ? x1 : -1e30f;
                const float p0 = __expf(x0);
                const float p1 = __expf(x1);
                lrow[r] += p0 + p1;
                s_p[w][row][m]      = f2bf(p0);
                s_p[w][row][16 + m] = f2bf(p1);
            }
            // P: C-layout -> A-layout via LDS (same-wave DS is in-order)
            __builtin_amdgcn_wave_barrier();
            const bf16x8 pa = *reinterpret_cast<const bf16x8*>(&s_p[w][m][quad * 8]);
            __builtin_amdgcn_wave_barrier();

            // --- PV from LDS V (swizzled read) ---
            #pragma unroll
            for (int f = 0; f < 8; ++f) {
                const bf16x8 vb = *(const bf16x8*)(vbp + (f * 16 + m) * 64 +
                                                   ((quad * 16) ^ vsw));
                o[f] = __builtin_amdgcn_mfma_f32_16x16x32_bf16(pa, vb, o[f], 0, 0, 0);
            }

            cur = nxt;   // no trailing barrier: triple buffer keeps the
                         // DMA-written buffer 2 tiles from any reader
        }

        // reduce l across the 16 columns held by lanes of each quad-row group
        float inv[4];
        #pragma unroll
        for (int r = 0; r < 4; ++r) {
            float l = lrow[r];
            l += __shfl_xor(l, 1, 64);
            l += __shfl_xor(l, 2, 64);
            l += __shfl_xor(l, 4, 64);
            l += __shfl_xor(l, 8, 64);
            inv[r] = 1.f / l;
        }
        #pragma unroll
        for (int f = 0; f < 8; ++f)
            #pragma unroll
            for (int r = 0; r < 4; ++r)
                ctx[(size_t)(b * Ss + q0 + quad * 4 + r) * Dd + h * HDd + f * 16 + m] =
                    f2bf(o[f][r] * inv[r]);

        // protect LDS buffers before next pi overwrites them
        __syncthreads();
    }
}

extern "C" void kernel_launch(void* const* d_in, const int* in_sizes, int n_in,
                              void* d_out, int out_size, void* d_ws, size_t ws_size,
                              hipStream_t stream) {
    const float* hidden = (const float*)d_in[0];
    const float* cosT   = (const float*)d_in[1];
    const float* sinT   = (const float*)d_in[2];
    const float* alibi  = (const float*)d_in[3];
    const float* amask  = (const float*)d_in[4];
    const float* wq     = (const float*)d_in[5];
    const float* wk     = (const float*)d_in[6];
    const float* wv     = (const float*)d_in[7];
    const float* wo     = (const float*)d_in[8];
    float* out = (float*)d_out;

    char* ws = (char*)d_ws;
    unsigned short* Abf   = (unsigned short*)(ws);              // 16,777,216
    unsigned short* wqT   = (unsigned short*)(ws + 16777216);   //  8,388,608
    unsigned short* kvT   = (unsigned short*)(ws + 25165824);   //  4,194,304
    unsigned short* woT   = (unsigned short*)(ws + 29360128);   //  8,388,608
    unsigned short* Qraw  = (unsigned short*)(ws + 37748736);   // 16,777,216
    unsigned short* KVraw = (unsigned short*)(ws + 54525952);   //  8,388,608
    unsigned short* VT    = (unsigned short*)(ws + 62914560);   //  4,194,304
    unsigned short* Ctx   = (unsigned short*)(ws + 67108864);   // 16,777,216
    // total: 83,886,080 B

    const int M = Bb * Ss;  // 4096

    cast_bf16<<<(M * Dd / 4) / 256, 256, 0, stream>>>(hidden, Abf);
    wt_cast<<<dim3(64, 64), 256, 0, stream>>>(wq, wqT, Dd, Dd);
    wt_cast<<<dim3(64, 16), 256, 0, stream>>>(wk, kvT, Dd, 512);
    wt_cast<<<dim3(64, 16), 256, 0, stream>>>(wv, kvT + (size_t)512 * Dd, Dd, 512);
    wt_cast<<<dim3(64, 64), 256, 0, stream>>>(wo, woT, Dd, Dd);

    gemm_bt<true><<<dim3(Dd / 128, M / 128), 256, 0, stream>>>(Abf, wqT, Qraw, M, Dd, Dd);
    gemm_bt<true><<<dim3(1024 / 128, M / 128), 256, 0, stream>>>(Abf, kvT, KVraw, M, 1024, Dd);

    const float scale = 0.08838834764831845f;  // 1/sqrt(128), folded into Q
    int totQ = Bb * Ss * Hh * 64;
    rope_bf<<<totQ / 256, 256, 0, stream>>>(Qraw, cosT, sinT, 4, Dd, scale, totQ);
    int totK = Bb * Ss * KVHh * 64;
    rope_bf<<<totK / 256, 256, 0, stream>>>(KVraw, cosT, sinT, 2, 1024, 1.0f, totK);

    vt_cast_bf<<<dim3(Ss / 32, HDd / 32, Bb * KVHh), 256, 0, stream>>>(KVraw, VT);

    flash_attn<<<dim3(64, KVHh, Bb), 256, 0, stream>>>(Qraw, KVraw, VT, alibi, amask, Ctx);

    gemm_bt<false><<<dim3(Dd / 128, M / 128), 256, 0, stream>>>(Ctx, woT, out, M, Dd, Dd);
}

// Round 6
// 363.211 us; speedup vs baseline: 1.3163x; 1.1492x over previous
//
#include <hip/hip_runtime.h>
#include <hip/hip_bf16.h>

#define Bb   2
#define Ss   2048
#define Dd   2048
#define Hh   16
#define KVHh 4
#define HDd  128
#define QKVW 3072   // fused Q|K|V row width

typedef __bf16 bf16x8 __attribute__((ext_vector_type(8)));
typedef float f32x4 __attribute__((ext_vector_type(4)));

__device__ __forceinline__ unsigned short f2bf(float f) {
    unsigned u = __float_as_uint(f);
    unsigned r = (u + 0x7FFFu + ((u >> 16) & 1u)) >> 16;   // RNE
    return (unsigned short)r;
}
__device__ __forceinline__ float bfu2f(unsigned short u) {
    return __uint_as_float(((unsigned)u) << 16);
}

// async global->LDS, 16B per lane; lds base must be wave-uniform (HW adds lane*16)
#define GLOAD16(g, l) __builtin_amdgcn_global_load_lds( \
    (const __attribute__((address_space(1))) unsigned int*)(g), \
    (__attribute__((address_space(3))) unsigned int*)(l), 16, 0, 0)

// fp32 -> bf16 elementwise, 4 elems/thread
__global__ __launch_bounds__(256)
void cast_bf16(const float* __restrict__ X, unsigned short* __restrict__ Y)
{
    int idx = blockIdx.x * 256 + threadIdx.x;
    float4 v = reinterpret_cast<const float4*>(X)[idx];
    ushort4 o;
    o.x = f2bf(v.x); o.y = f2bf(v.y); o.z = f2bf(v.z); o.w = f2bf(v.w);
    reinterpret_cast<ushort4*>(Y)[idx] = o;
}

// All four weight transposes in ONE dispatch (saves 3 launches).
// wq -> wqkvT rows 0..2047, wk -> rows 2048..2559, wv -> rows 2560..3071,
// wo -> woT. K is always 2048.
__global__ __launch_bounds__(256)
void wt_cast_all(const float* __restrict__ wq, const float* __restrict__ wk,
                 const float* __restrict__ wv, const float* __restrict__ wo,
                 unsigned short* __restrict__ wqkvT, unsigned short* __restrict__ woT)
{
    __shared__ float tile[32][33];
    int id = blockIdx.x;
    const float* W; unsigned short* WT; int N, kx, ny;
    if (id < 4096)      {            W = wq; WT = wqkvT;                        N = 2048; kx = id & 63; ny = id >> 6; }
    else if (id < 5120) { id -= 4096; W = wk; WT = wqkvT + (size_t)2048 * 2048; N = 512;  kx = id & 63; ny = id >> 6; }
    else if (id < 6144) { id -= 5120; W = wv; WT = wqkvT + (size_t)2560 * 2048; N = 512;  kx = id & 63; ny = id >> 6; }
    else                { id -= 6144; W = wo; WT = woT;                         N = 2048; kx = id & 63; ny = id >> 6; }
    const int K = 2048;
    int k0 = kx * 32, n0 = ny * 32;
    int tx = threadIdx.x & 31, ty = threadIdx.x >> 5;   // 32 x 8
    #pragma unroll
    for (int i = 0; i < 32; i += 8)
        tile[ty + i][tx] = W[(size_t)(k0 + ty + i) * N + n0 + tx];
    __syncthreads();
    #pragma unroll
    for (int i = 0; i < 32; i += 8)
        WT[(size_t)(n0 + ty + i) * K + k0 + tx] = f2bf(tile[tx][ty + i]);
}

// C[M,N] = A[M,K] @ BT[N,K]^T, bf16 in, fp32 accumulate, fp32 or bf16 out.
// 128x128 tile, BK=32, 4 waves (2x2 of 64x64), global_load_lds staging.
template<bool BF16OUT>
__global__ __launch_bounds__(256)
void gemm_bt(const unsigned short* __restrict__ A,
             const unsigned short* __restrict__ BT,
             void* __restrict__ Cv, int M, int N, int K)
{
    __shared__ __align__(16) unsigned short sA[128 * 32];
    __shared__ __align__(16) unsigned short sB[128 * 32];
    const int tid  = threadIdx.x;
    const int wave = tid >> 6;
    const int lane = tid & 63;
    const int m    = lane & 15;
    const int quad = lane >> 4;
    const int wm   = wave >> 1, wn = wave & 1;
    const int m0   = blockIdx.y * 128, n0 = blockIdx.x * 128;

    const int srow = tid >> 2;          // 0..63
    const int skg  = (tid & 3) * 8;     // k-group *8 elems

    f32x4 acc[4][4];
    #pragma unroll
    for (int r = 0; r < 4; ++r)
        #pragma unroll
        for (int c = 0; c < 4; ++c) acc[r][c] = (f32x4){0.f, 0.f, 0.f, 0.f};

    const unsigned short* pa = A  + (size_t)(m0 + srow) * K + skg;
    const unsigned short* pb = BT + (size_t)(n0 + srow) * K + skg;
    unsigned short* la = &sA[wave * 16 * 32];   // wave-uniform LDS base
    unsigned short* lb = &sB[wave * 16 * 32];

    for (int k0 = 0; k0 < K; k0 += 32) {
        GLOAD16(pa + k0, la);
        GLOAD16(pa + (size_t)64 * K + k0, la + 64 * 32);
        GLOAD16(pb + k0, lb);
        GLOAD16(pb + (size_t)64 * K + k0, lb + 64 * 32);
        __syncthreads();
        bf16x8 af[4], bfr[4];
        #pragma unroll
        for (int r = 0; r < 4; ++r)
            af[r] = *reinterpret_cast<const bf16x8*>(
                &sA[(wm * 64 + r * 16 + m) * 32 + quad * 8]);
        #pragma unroll
        for (int c = 0; c < 4; ++c)
            bfr[c] = *reinterpret_cast<const bf16x8*>(
                &sB[(wn * 64 + c * 16 + m) * 32 + quad * 8]);
        #pragma unroll
        for (int r = 0; r < 4; ++r)
            #pragma unroll
            for (int c = 0; c < 4; ++c)
                acc[r][c] = __builtin_amdgcn_mfma_f32_16x16x32_bf16(
                    af[r], bfr[c], acc[r][c], 0, 0, 0);
        __syncthreads();
    }
    // C/D layout: row = quad*4 + e, col = m
    #pragma unroll
    for (int r = 0; r < 4; ++r)
        #pragma unroll
        for (int c = 0; c < 4; ++c)
            #pragma unroll
            for (int e = 0; e < 4; ++e) {
                size_t row = m0 + wm * 64 + r * 16 + quad * 4 + e;
                size_t col = n0 + wn * 64 + c * 16 + m;
                if (BF16OUT)
                    ((unsigned short*)Cv)[row * N + col] = f2bf(acc[r][c][e]);
                else
                    ((float*)Cv)[row * N + col] = acc[r][c][e];
            }
}

// RoPE on fused QKV buffer: heads 0..15 = Q (scaled by 1/sqrt(128)),
// heads 16..19 = K (cols 2048..2559). One dispatch (saves a launch).
// grid (1024, 20), block 256 = 4 rows x 64 lanes.
__global__ __launch_bounds__(256)
void rope_all(unsigned short* __restrict__ qkv, const float* __restrict__ cosT,
              const float* __restrict__ sinT)
{
    const int h   = blockIdx.y;
    const int row = blockIdx.x * 4 + (threadIdx.x >> 6);
    const int i   = threadIdx.x & 63;
    const int s   = row & (Ss - 1);
    const float scale = (h < Hh) ? 0.08838834764831845f : 1.0f;
    unsigned short* xp = qkv + (size_t)row * QKVW + h * HDd;
    float x1 = bfu2f(xp[i]);
    float x2 = bfu2f(xp[i + 64]);
    float c1 = cosT[s * HDd + i];
    float c2 = cosT[s * HDd + i + 64];
    float s1 = sinT[s * HDd + i];
    float s2 = sinT[s * HDd + i + 64];
    xp[i]      = f2bf((x1 * c1 - x2 * s1) * scale);
    xp[i + 64] = f2bf((x2 * c2 + x1 * s2) * scale);
}

// V (cols 2560.. of QKVraw [B*S,3072] bf16) -> VT [B,KVH,128,S] bf16
__global__ __launch_bounds__(256)
void vt_cast_bf(const unsigned short* __restrict__ KV,
                unsigned short* __restrict__ VT)
{
    __shared__ unsigned short tile[32][34];
    int st = blockIdx.x * 32, dt = blockIdx.y * 32;
    int bk = blockIdx.z;
    int b = bk >> 2, kvh = bk & 3;
    int tx = threadIdx.x & 31, ty = threadIdx.x >> 5;   // 32 x 8
    #pragma unroll
    for (int i = 0; i < 32; i += 8)
        tile[ty + i][tx] = KV[(size_t)(b * Ss + st + ty + i) * QKVW + 2560 + kvh * HDd + dt + tx];
    __syncthreads();
    #pragma unroll
    for (int i = 0; i < 32; i += 8)
        VT[(((size_t)b * KVHh + kvh) * HDd + dt + ty + i) * Ss + st + tx] =
            tile[tx][ty + i];
}

// Flash attention, max-free softmax.
//
// Round-11 = round-10 pipeline + UNION LOOP: round-10 measured as
// LDS-BW-bound (~96KB LDS traffic per block-tile, ~61us floor of 99us).
// Each wave now owns BOTH pair members {qtA, 127-qtA} (16 rows each) in a
// single k-walk of ntB tiles: K/V LDS fragments and DMA staging are paid
// once per walked tile and feed member B always + member A while kt<ntA.
// Walked tiles/block: 65 -> 33..64 (avg ~49). Per-block load varies, so
// qtA is STRIPED (x&1 ? 63-x/2 : x/2, z-flipped) making both plausible
// co-residency pairings (id,id+1 and id,id+256) sum to ~97 walked tiles
// (round-3's imbalance bug explicitly avoided).
// vmcnt counts: waves 0-1 stage K(2)+V(2)+alibiA(0/1), waves 2-3 K+V+alibiB
// -> wait vmcnt(5) or (4), wave-uniform. V-frags hoisted to regs, reused
// by member A. Zero compiler-managed vector loads in the loop body.
__global__ __launch_bounds__(256, 2)
void flash_attn(const unsigned short* __restrict__ qkv,  // [B*S,3072] bf16
                const unsigned short* __restrict__ VT,   // [B,KVH,128,S] bf16
                const float* __restrict__ alibi,         // [B,S,S]
                const float* __restrict__ amask,         // [B,S]
                unsigned short* __restrict__ ctx)        // [B*S,2048] bf16
{
    __shared__ __align__(16) unsigned short kbuf[3][32 * 128];  // row=key, 256B/row, swizzled
    __shared__ __align__(16) unsigned short vbuf[3][128 * 32];  // row=d, 64B/row, swizzled
    __shared__ __align__(16) float          abuf[3][2][512];    // alibi slabs [A/B][qrow][key]
    __shared__ __align__(16) float          am_lds[Ss];         // amask row for this b
    __shared__ unsigned short s_p[4][16][56];                   // per-wave P scratch

    const int tid  = threadIdx.x;
    const int w    = tid >> 6;
    const int m    = tid & 15;
    const int quad = (tid & 63) >> 4;

    const int kvh = blockIdx.y;
    const int b   = blockIdx.z;
    const int h   = kvh * 4 + w;        // this wave's head

    // striped + z-flipped pair assignment (load balance under id+1 or id+256)
    const int x    = blockIdx.x;
    const int qtA0 = (x & 1) ? (63 - (x >> 1)) : (x >> 1);
    const int qtA  = b ? (63 - qtA0) : qtA0;
    const int qtB  = 127 - qtA;
    const int qA0  = qtA * 16, qB0 = qtB * 16;
    const int ntA  = (qA0 + 47) >> 5;   // 1..32
    const int ntB  = (qB0 + 47) >> 5;   // 33..64  (ntA < ntB always)

    const unsigned short* vt0 = VT + ((size_t)b * KVHh + kvh) * HDd * Ss;
    const float* amrow = amask + (size_t)b * Ss;
    const float* arowA = alibi + ((size_t)b * Ss + qA0) * Ss;
    const float* arowB = alibi + ((size_t)b * Ss + qB0) * Ss;
    const unsigned short* kgbase = qkv + (size_t)b * Ss * QKVW + 2048 + kvh * HDd;

    // staging geometry (DMA dest linear in thread order)
    const int krow_s = tid >> 4;                                  // K row 0..15 (+16)
    const int koff_b = ((tid & 15) * 16) ^ ((krow_s & 7) << 4);   // pre-swizzled src byte
    const int vrow_s = tid >> 2;                                  // V row 0..63 (+64)
    const int vchk_s = (tid & 3) ^ ((vrow_s >> 1) & 3);           // pre-swizzled chunk
    const int dstw   = w * 512;                                   // wave's 1KB stripe

    // ---- prologue: amask -> LDS, Q fragments for both members ----
    {
        const float* ag = amrow + tid * 4;
        GLOAD16(ag,        am_lds + w * 256);
        GLOAD16(ag + 1024, am_lds + 1024 + w * 256);
    }
    bf16x8 qaA[4], qaB[4];
    {
        const unsigned short* qrA = qkv + (size_t)(b * Ss + qA0 + m) * QKVW + h * HDd;
        const unsigned short* qrB = qkv + (size_t)(b * Ss + qB0 + m) * QKVW + h * HDd;
        #pragma unroll
        for (int c = 0; c < 4; ++c) {
            qaA[c] = *reinterpret_cast<const bf16x8*>(qrA + c * 32 + quad * 8);
            qaB[c] = *reinterpret_cast<const bf16x8*>(qrB + c * 32 + quad * 8);
        }
    }

    f32x4 oA[8], oB[8];
    #pragma unroll
    for (int f = 0; f < 8; ++f) {
        oA[f] = (f32x4){0.f, 0.f, 0.f, 0.f};
        oB[f] = (f32x4){0.f, 0.f, 0.f, 0.f};
    }
    float lA[4] = {0.f, 0.f, 0.f, 0.f}, lB[4] = {0.f, 0.f, 0.f, 0.f};

    // stage K/V (+alibi slabs) for tile at key kn into buffer buf
    auto STAGE = [&](int kn, int buf, bool aact) {
        const unsigned short* kg =
            kgbase + (size_t)(kn + krow_s) * QKVW + (koff_b >> 1);
        GLOAD16(kg,              &kbuf[buf][dstw]);
        GLOAD16(kg + 16 * QKVW,  &kbuf[buf][2048 + dstw]);
        const unsigned short* vg = vt0 + (size_t)vrow_s * Ss + kn + vchk_s * 8;
        GLOAD16(vg,             &vbuf[buf][dstw]);
        GLOAD16(vg + 64 * Ss,   &vbuf[buf][2048 + dstw]);
        if (tid < 128) {
            if (aact) {
                const float* ag = arowA + (size_t)(tid >> 3) * Ss + kn + (tid & 7) * 4;
                GLOAD16(ag, &abuf[buf][0][w * 256]);
            }
        } else {
            const float* ag = arowB + (size_t)((tid - 128) >> 3) * Ss + kn + (tid & 7) * 4;
            GLOAD16(ag, &abuf[buf][1][(w - 2) * 256]);
        }
    };

    STAGE(0, 0, true);
    asm volatile("s_waitcnt vmcnt(0)" ::: "memory");
    __syncthreads();

    int cur = 0;
    #pragma unroll 1
    for (int kt = 0; kt < ntB; ++kt) {
        const int k0  = kt * 32;
        const int nxt = (cur == 2) ? 0 : cur + 1;
        const bool aact = kt < ntA;

        if (kt + 1 < ntB) {
            const bool aactn = (kt + 1) < ntA;
            STAGE(k0 + 32, nxt, aactn);
            if (w < 2) {
                if (aactn) asm volatile("s_waitcnt vmcnt(5)" ::: "memory");
                else       asm volatile("s_waitcnt vmcnt(4)" ::: "memory");
            } else       asm volatile("s_waitcnt vmcnt(5)" ::: "memory");
        } else {
            asm volatile("s_waitcnt vmcnt(0)" ::: "memory");
        }
        __builtin_amdgcn_s_barrier();        // raw: does NOT drain vmcnt
        __builtin_amdgcn_sched_barrier(0);   // pin: no ds_read hoisted above

        const float am0 = am_lds[k0 + m];
        const float am1 = am_lds[k0 + 16 + m];

        // --- shared K fragments (swizzled) + hoisted V fragments ---
        const char* kb  = (const char*)&kbuf[cur][0];
        const char* vbp = (const char*)&vbuf[cur][0];
        const int  ksw  = (m & 7) << 4;
        const int  vsw  = ((m >> 1) & 3) << 4;
        bf16x8 kf0[4], kf1[4];
        #pragma unroll
        for (int c = 0; c < 4; ++c) {
            kf0[c] = *(const bf16x8*)(kb + m * 256        + ((c * 64 + quad * 16) ^ ksw));
            kf1[c] = *(const bf16x8*)(kb + (16 + m) * 256 + ((c * 64 + quad * 16) ^ ksw));
        }
        bf16x8 vf[8];
        #pragma unroll
        for (int f = 0; f < 8; ++f)
            vf[f] = *(const bf16x8*)(vbp + (f * 16 + m) * 64 + ((quad * 16) ^ vsw));

        // ---------------- member B (always active) ----------------
        {
            f32x4 s0 = {0.f, 0.f, 0.f, 0.f}, s1 = {0.f, 0.f, 0.f, 0.f};
            #pragma unroll
            for (int c = 0; c < 4; ++c) {
                s0 = __builtin_amdgcn_mfma_f32_16x16x32_bf16(qaB[c], kf0[c], s0, 0, 0, 0);
                s1 = __builtin_amdgcn_mfma_f32_16x16x32_bf16(qaB[c], kf1[c], s1, 0, 0, 0);
            }
            #pragma unroll
            for (int r = 0; r < 4; ++r) {
                const int row = quad * 4 + r;
                const int qi  = qB0 + row;
                float x0 = s0[r] + abuf[cur][1][row * 32 + m]      + am0;
                float x1 = s1[r] + abuf[cur][1][row * 32 + 16 + m] + am1;
                x0 = (k0 + m      <= qi) ? x0 : -1e30f;
                x1 = (k0 + 16 + m <= qi) ? x1 : -1e30f;
                const float p0 = __expf(x0);
                const float p1 = __expf(x1);
                lB[r] += p0 + p1;
                s_p[w][row][m]      = f2bf(p0);
                s_p[w][row][16 + m] = f2bf(p1);
            }
            __builtin_amdgcn_wave_barrier();
            const bf16x8 pa = *reinterpret_cast<const bf16x8*>(&s_p[w][m][quad * 8]);
            __builtin_amdgcn_wave_barrier();
            #pragma unroll
            for (int f = 0; f < 8; ++f)
                oB[f] = __builtin_amdgcn_mfma_f32_16x16x32_bf16(pa, vf[f], oB[f], 0, 0, 0);
        }

        // ---------------- member A (while kt < ntA) ----------------
        if (aact) {
            f32x4 s0 = {0.f, 0.f, 0.f, 0.f}, s1 = {0.f, 0.f, 0.f, 0.f};
            #pragma unroll
            for (int c = 0; c < 4; ++c) {
                s0 = __builtin_amdgcn_mfma_f32_16x16x32_bf16(qaA[c], kf0[c], s0, 0, 0, 0);
                s1 = __builtin_amdgcn_mfma_f32_16x16x32_bf16(qaA[c], kf1[c], s1, 0, 0, 0);
            }
            #pragma unroll
            for (int r = 0; r < 4; ++r) {
                const int row = quad * 4 + r;
                const int qi  = qA0 + row;
                float x0 = s0[r] + abuf[cur][0][row * 32 + m]      + am0;
                float x1 = s1[r] + abuf[cur][0][row * 32 + 16 + m] + am1;
                x0 = (k0 + m      <= qi) ? x0 : -1e30f;
                x1 = (k0 + 16 + m <= qi) ? x1 : -1e30f;
                const float p0 = __expf(x0);
                const float p1 = __expf(x1);
                lA[r] += p0 + p1;
                s_p[w][row][m]      = f2bf(p0);
                s_p[w][row][16 + m] = f2bf(p1);
            }
            __builtin_amdgcn_wave_barrier();
            const bf16x8 pa = *reinterpret_cast<const bf16x8*>(&s_p[w][m][quad * 8]);
            __builtin_amdgcn_wave_barrier();
            #pragma unroll
            for (int f = 0; f < 8; ++f)
                oA[f] = __builtin_amdgcn_mfma_f32_16x16x32_bf16(pa, vf[f], oA[f], 0, 0, 0);
        }

        cur = nxt;   // triple buffer: DMA-written buffer is 2 tiles from readers
    }

    // epilogue: normalize + write both members
    float invA[4], invB[4];
    #pragma unroll
    for (int r = 0; r < 4; ++r) {
        float la = lA[r], lb = lB[r];
        la += __shfl_xor(la, 1, 64); lb += __shfl_xor(lb, 1, 64);
        la += __shfl_xor(la, 2, 64); lb += __shfl_xor(lb, 2, 64);
        la += __shfl_xor(la, 4, 64); lb += __shfl_xor(lb, 4, 64);
        la += __shfl_xor(la, 8, 64); lb += __shfl_xor(lb, 8, 64);
        invA[r] = 1.f / la; invB[r] = 1.f / lb;
    }
    #pragma unroll
    for (int f = 0; f < 8; ++f)
        #pragma unroll
        for (int r = 0; r < 4; ++r) {
            ctx[(size_t)(b * Ss + qA0 + quad * 4 + r) * Dd + h * HDd + f * 16 + m] =
                f2bf(oA[f][r] * invA[r]);
            ctx[(size_t)(b * Ss + qB0 + quad * 4 + r) * Dd + h * HDd + f * 16 + m] =
                f2bf(oB[f][r] * invB[r]);
        }
}

extern "C" void kernel_launch(void* const* d_in, const int* in_sizes, int n_in,
                              void* d_out, int out_size, void* d_ws, size_t ws_size,
                              hipStream_t stream) {
    const float* hidden = (const float*)d_in[0];
    const float* cosT   = (const float*)d_in[1];
    const float* sinT   = (const float*)d_in[2];
    const float* alibi  = (const float*)d_in[3];
    const float* amask  = (const float*)d_in[4];
    const float* wq     = (const float*)d_in[5];
    const float* wk     = (const float*)d_in[6];
    const float* wv     = (const float*)d_in[7];
    const float* wo     = (const float*)d_in[8];
    float* out = (float*)d_out;

    char* ws = (char*)d_ws;
    unsigned short* Abf    = (unsigned short*)(ws);              // 16,777,216
    unsigned short* wqkvT  = (unsigned short*)(ws + 16777216);   // 12,582,912  [3072][2048]
    unsigned short* woT    = (unsigned short*)(ws + 29360128);   //  8,388,608
    unsigned short* QKVraw = (unsigned short*)(ws + 37748736);   // 25,165,824  [4096][3072]
    unsigned short* VT     = (unsigned short*)(ws + 62914560);   //  4,194,304
    unsigned short* Ctx    = (unsigned short*)(ws + 67108864);   // 16,777,216
    // total: 83,886,080 B

    const int M = Bb * Ss;  // 4096

    cast_bf16<<<(M * Dd / 4) / 256, 256, 0, stream>>>(hidden, Abf);
    wt_cast_all<<<10240, 256, 0, stream>>>(wq, wk, wv, wo, wqkvT, woT);

    // fused Q|K|V projection: one GEMM, A read once
    gemm_bt<true><<<dim3(QKVW / 128, M / 128), 256, 0, stream>>>(Abf, wqkvT, QKVraw, M, QKVW, Dd);

    rope_all<<<dim3(M / 4, 20), 256, 0, stream>>>(QKVraw, cosT, sinT);

    vt_cast_bf<<<dim3(Ss / 32, HDd / 32, Bb * KVHh), 256, 0, stream>>>(QKVraw, VT);

    flash_attn<<<dim3(64, KVHh, Bb), 256, 0, stream>>>(QKVraw, VT, alibi, amask, Ctx);

    gemm_bt<false><<<dim3(Dd / 128, M / 128), 256, 0, stream>>>(Ctx, woT, out, M, Dd, Dd);
}